// Round 8
// baseline (203.412 us; speedup 1.0000x reference)
//
#include <hip/hip_runtime.h>
#include <math.h>
#include <stdint.h>

#define T_STEPS 256
#define BS      512
#define N       2048
#define BLOCK   256               // 4 waves per batch element, EPT=8
#define FUDGE   1e-4f

// R16: R15's 4-wave asm failed with absmax == max|ref| (output never stored).
// Prime suspects were the two noncanonical exec constructs gating the store
// (readfirstlane->s_cmp->branch; manual exec_lo/hi masking). This round keeps
// R15's performance structure (4 waves, EPT=8, pinned coeffs, DPP reduce,
// parity-LDS exchange, 1 barrier/step) but rebuilds ALL lane gating in
// canonical form: v_cmp -> SGPR-pair masks computed once in the prologue,
// s_and_saveexec_b64 around the ds_write2 and the out store (waves 1-3 run
// the store with exec=0, architecturally dropped; zero branches).
__global__ __launch_bounds__(BLOCK, 2)
void legacy_elbo_scan_kernel(
    const float* __restrict__ noises,   // [T, BS]
    const float* __restrict__ ys,       // [T]
    const float* __restrict__ qs,       // [T]
    const float* __restrict__ z_biases, // [N]
    const float* __restrict__ w_in,     // [N]
    const float* __restrict__ w_inq,    // [N]
    const float* __restrict__ p_llr,
    const float* __restrict__ p_llrd,
    const float* __restrict__ p_sigb,
    const float* __restrict__ p_oscale,
    const float* __restrict__ p_ufs,
    const float* __restrict__ p_lwd,
    const float* __restrict__ p_qscale,
    const float* __restrict__ p_tauq,
    const float* __restrict__ p_tauy,
    float* __restrict__ out)            // [T, BS]
{
    const int tid = threadIdx.x;
    const int blk = blockIdx.x;

    __shared__ float red_lds[16];       // [parity 2][wave 4][su,sh] = 64 B
    if (tid < 16) red_lds[tid] = 0.0f;  // keep the allocation live, offset 0
    __syncthreads();

    const float sigb    = p_sigb[0];
    const float lr0     = expf(p_llr[0]);
    const float lr_decay= expf(p_llrd[0]);
    const float wd      = expf(p_lwd[0]);
    const float rwd     = 1.0f / wd;
    const float tauq    = 1.0f + log1pf(expf(p_tauq[0]));
    const float tauy    = 1.0f + log1pf(expf(p_tauy[0]));
    const float omtq    = 1.0f - tauq;
    const float omty    = 1.0f - tauy;
    const float qscale  = p_qscale[0];
    const float ufs     = p_ufs[0];
    const float oscale  = p_oscale[0];
    // __expf(x) == exp2(x * log2(e)); fold -lr_decay into the multiplier.
    const float nld2    = -lr_decay * 1.4426950408889634f;

    const float* nzp = noises + blk;    // uniform: per-block noise column base
    const int    ovo = blk * 4;         // byte offset of out[0*BS+blk]

    asm volatile(
        // -------- init: ids, masks, LDS addrs, coeff loads -> v40..v63 ------
        "v_lshrrev_b32 v3, 6, %[vtid]\n\t"          // wid (0..3)
        "v_lshlrev_b32 v4, 3, v3\n\t"               // ds write addr = wid*8
        "v_and_b32 v7, 63, %[vtid]\n\t"             // lane id
        "v_cmp_eq_u32 vcc, 63, v7\n\t"              // lane-63 mask
        "s_mov_b64 s[74:75], vcc\n\t"
        "v_cmp_eq_u32 vcc, 0, %[vtid]\n\t"          // tid==0 mask (wave0 only)
        "s_mov_b64 s[76:77], vcc\n\t"
        "v_mov_b32 v5, 0\n\t"                       // ds read base (parity 0)
        "v_lshlrev_b32 v1, 4, %[vtid]\n\t"          // tid*16 bytes
        "v_add_u32 v2, 0x1000, v1\n\t"              // +4096 for chunk 1
        "global_load_dwordx4 v[40:43], v1, %[pzb]\n\t"
        "global_load_dwordx4 v[44:47], v2, %[pzb]\n\t"
        "global_load_dwordx4 v[48:51], v1, %[pwi]\n\t"
        "global_load_dwordx4 v[52:55], v2, %[pwi]\n\t"
        "global_load_dwordx4 v[56:59], v1, %[pwq]\n\t"
        "global_load_dwordx4 v[60:63], v2, %[pwq]\n\t"
        "s_waitcnt vmcnt(0)\n\t"
        // scale biases by sigma_b
        "v_mul_f32 v40, %[osg], v40\n\t"  "v_mul_f32 v41, %[osg], v41\n\t"
        "v_mul_f32 v42, %[osg], v42\n\t"  "v_mul_f32 v43, %[osg], v43\n\t"
        "v_mul_f32 v44, %[osg], v44\n\t"  "v_mul_f32 v45, %[osg], v45\n\t"
        "v_mul_f32 v46, %[osg], v46\n\t"  "v_mul_f32 v47, %[osg], v47\n\t"
        // zero w_out state v64..v71
        "v_mov_b32 v64, 0\n\t" "v_mov_b32 v65, 0\n\t" "v_mov_b32 v66, 0\n\t" "v_mov_b32 v67, 0\n\t"
        "v_mov_b32 v68, 0\n\t" "v_mov_b32 v69, 0\n\t" "v_mov_b32 v70, 0\n\t" "v_mov_b32 v71, 0\n\t"
        // state: qlp v20, ylp v21, u v22, e v23, lr_mult v24, sp v25, rsp v26
        "v_mov_b32 v20, 0\n\t" "v_mov_b32 v21, 0\n\t" "v_mov_b32 v22, 0\n\t" "v_mov_b32 v23, 0\n\t"
        "v_mov_b32 v24, 1.0\n\t" "v_mov_b32 v25, 1.0\n\t" "v_mov_b32 v26, 1.0\n\t"
        "v_mov_b32 v6, %[ovo]\n\t"                  // out byte-offset
        "s_mov_b32 s60, 0\n\t"                      // t
        "s_mov_b32 s61, 0\n\t"                      // y/q byte offset
        "s_mov_b32 s62, 0\n\t"                      // nz byte offset
        "s_load_dword s66, %[pys], s61\n\t"
        "s_load_dword s67, %[pqs], s61\n\t"
        "s_load_dword s68, %[pnz], s62\n\t"
        "s_waitcnt lgkmcnt(0)\n\t"
        // ---------------- main scan loop ------------------------------------
        "Lelbo2:\n\t"
        // prefetch next step's scalars (clamped at T-1)
        "s_add_u32 s63, s61, 4\n\t"
        "s_min_u32 s63, s63, 0x3fc\n\t"
        "s_add_u32 s64, s62, 0x800\n\t"
        "s_min_u32 s64, s64, 0x7f800\n\t"
        "s_load_dword s69, %[pys], s63\n\t"
        "s_load_dword s70, %[pqs], s63\n\t"
        "s_load_dword s71, %[pnz], s64\n\t"
        // qlp = omtq*qlp + tauq*q ; qsc pair v[10:11]
        "v_mov_b32 v30, s67\n\t"
        "v_mul_f32 v20, %[omq], v20\n\t"
        "v_fmac_f32 v20, %[otq], v30\n\t"
        "v_mul_f32 v10, %[oq], v20\n\t"
        "v_mov_b32 v11, v10\n\t"
        // x = e + nz + ufs*u ; pair v[8:9]
        "v_mov_b32 v8, s68\n\t"
        "v_add_f32 v8, v23, v8\n\t"
        "v_fmac_f32 v8, %[ouf], v22\n\t"
        "v_mov_b32 v9, v8\n\t"
        // zero accumulators su v[12:13], sh v[14:15]
        "v_mov_b32 v12, 0\n\t" "v_mov_b32 v13, 0\n\t"
        "v_mov_b32 v14, 0\n\t" "v_mov_b32 v15, 0\n\t"
        // h = relu(cb + x*cw + qsc*cq)  (4 packed pairs)
        "v_pk_fma_f32 v[72:73], v[10:11], v[56:57], v[40:41]\n\t"
        "v_pk_fma_f32 v[74:75], v[10:11], v[58:59], v[42:43]\n\t"
        "v_pk_fma_f32 v[76:77], v[10:11], v[60:61], v[44:45]\n\t"
        "v_pk_fma_f32 v[78:79], v[10:11], v[62:63], v[46:47]\n\t"
        "v_pk_fma_f32 v[72:73], v[8:9], v[48:49], v[72:73]\n\t"
        "v_pk_fma_f32 v[74:75], v[8:9], v[50:51], v[74:75]\n\t"
        "v_pk_fma_f32 v[76:77], v[8:9], v[52:53], v[76:77]\n\t"
        "v_pk_fma_f32 v[78:79], v[8:9], v[54:55], v[78:79]\n\t"
        "v_max_f32 v72, 0, v72\n\t" "v_max_f32 v73, 0, v73\n\t"
        "v_max_f32 v74, 0, v74\n\t" "v_max_f32 v75, 0, v75\n\t"
        "v_max_f32 v76, 0, v76\n\t" "v_max_f32 v77, 0, v77\n\t"
        "v_max_f32 v78, 0, v78\n\t" "v_max_f32 v79, 0, v79\n\t"
        // su += v.h ; sh += h.h (interleaved chains)
        "v_pk_fma_f32 v[12:13], v[64:65], v[72:73], v[12:13]\n\t"
        "v_pk_fma_f32 v[14:15], v[72:73], v[72:73], v[14:15]\n\t"
        "v_pk_fma_f32 v[12:13], v[66:67], v[74:75], v[12:13]\n\t"
        "v_pk_fma_f32 v[14:15], v[74:75], v[74:75], v[14:15]\n\t"
        "v_pk_fma_f32 v[12:13], v[68:69], v[76:77], v[12:13]\n\t"
        "v_pk_fma_f32 v[14:15], v[76:77], v[76:77], v[14:15]\n\t"
        "v_pk_fma_f32 v[12:13], v[70:71], v[78:79], v[12:13]\n\t"
        "v_pk_fma_f32 v[14:15], v[78:79], v[78:79], v[14:15]\n\t"
        // horizontal: su v12, sh v14
        "v_add_f32 v12, v12, v13\n\t"
        "v_add_f32 v14, v14, v15\n\t"
        // wave reduce to lane 63 (DPP), su v12/tmp v30, sh v14/tmp v31
        "s_nop 1\n\t"
        "v_mov_b32_dpp v30, v12 row_shr:1 row_mask:0xf bank_mask:0xf\n\t"
        "v_mov_b32_dpp v31, v14 row_shr:1 row_mask:0xf bank_mask:0xf\n\t"
        "v_add_f32 v12, v12, v30\n\t"
        "v_add_f32 v14, v14, v31\n\t"
        "s_nop 0\n\t"
        "v_mov_b32_dpp v30, v12 row_shr:2 row_mask:0xf bank_mask:0xf\n\t"
        "v_mov_b32_dpp v31, v14 row_shr:2 row_mask:0xf bank_mask:0xf\n\t"
        "v_add_f32 v12, v12, v30\n\t"
        "v_add_f32 v14, v14, v31\n\t"
        "s_nop 0\n\t"
        "v_mov_b32_dpp v30, v12 row_shr:4 row_mask:0xf bank_mask:0xf\n\t"
        "v_mov_b32_dpp v31, v14 row_shr:4 row_mask:0xf bank_mask:0xf\n\t"
        "v_add_f32 v12, v12, v30\n\t"
        "v_add_f32 v14, v14, v31\n\t"
        "s_nop 0\n\t"
        "v_mov_b32_dpp v30, v12 row_shr:8 row_mask:0xf bank_mask:0xf\n\t"
        "v_mov_b32_dpp v31, v14 row_shr:8 row_mask:0xf bank_mask:0xf\n\t"
        "v_add_f32 v12, v12, v30\n\t"
        "v_add_f32 v14, v14, v31\n\t"
        "s_nop 0\n\t"
        "v_mov_b32_dpp v30, v12 row_bcast:15 row_mask:0xf bank_mask:0xf\n\t"
        "v_mov_b32_dpp v31, v14 row_bcast:15 row_mask:0xf bank_mask:0xf\n\t"
        "v_add_f32 v12, v12, v30\n\t"
        "v_add_f32 v14, v14, v31\n\t"
        "s_nop 0\n\t"
        "v_mov_b32_dpp v30, v12 row_bcast:31 row_mask:0xf bank_mask:0xf\n\t"
        "v_mov_b32_dpp v31, v14 row_bcast:31 row_mask:0xf bank_mask:0xf\n\t"
        "v_add_f32 v12, v12, v30\n\t"
        "v_add_f32 v14, v14, v31\n\t"
        "s_nop 1\n\t"
        // lane 63 publishes this wave's partials {su, sh} to LDS (canonical mask)
        "s_and_saveexec_b64 s[72:73], s[74:75]\n\t"
        "ds_write2_b32 v4, v12, v14 offset0:0 offset1:1\n\t"
        "s_mov_b64 exec, s[72:73]\n\t"
        "s_waitcnt lgkmcnt(0)\n\t"
        "s_barrier\n\t"
        // broadcast-read all 4 waves' partials, combine
        "ds_read_b128 v[32:35], v5\n\t"
        "ds_read_b128 v[36:39], v5 offset:16\n\t"
        "s_waitcnt lgkmcnt(0)\n\t"
        "v_pk_add_f32 v[32:33], v[32:33], v[34:35]\n\t"
        "v_pk_add_f32 v[36:37], v[36:37], v[38:39]\n\t"
        "v_pk_add_f32 v[32:33], v[32:33], v[36:37]\n\t"   // su_t v32, sh_t v33
        // u = sp * su_t
        "v_mul_f32 v22, v25, v32\n\t"
        // store oscale*u from tid 0 only (exec-predicated; no branch)
        "v_mul_f32 v30, %[oos], v22\n\t"
        "s_and_saveexec_b64 s[72:73], s[76:77]\n\t"
        "global_store_dword v6, v30, %[pou]\n\t"
        "s_mov_b64 exec, s[72:73]\n\t"
        "v_add_u32 v6, 0x800, v6\n\t"               // next row (+BS*4)
        // ylp, e, el, c
        "v_mov_b32 v30, s66\n\t"
        "v_mul_f32 v21, %[omy], v21\n\t"
        "v_fmac_f32 v21, %[oty], v30\n\t"
        "v_sub_f32 v23, v21, v22\n\t"               // e = ylp - u
        "v_mul_f32 v27, %[olr], v23\n\t"
        "v_mul_f32 v27, v27, v24\n\t"               // el
        "v_mul_f32 v28, v27, v26\n\t"               // c = el*rsp
        "v_mov_b32 v29, v28\n\t"
        // v += c*h (4 packed)
        "v_pk_fma_f32 v[64:65], v[28:29], v[72:73], v[64:65]\n\t"
        "v_pk_fma_f32 v[66:67], v[28:29], v[74:75], v[66:67]\n\t"
        "v_pk_fma_f32 v[68:69], v[28:29], v[76:77], v[68:69]\n\t"
        "v_pk_fma_f32 v[70:71], v[28:29], v[78:79], v[70:71]\n\t"
        // lr_mult *= exp2(nld2 * sqrt(el^2*sh_t + FUDGE)) ; sp, rsp
        "v_mul_f32 v30, v27, v27\n\t"
        "v_mul_f32 v30, v33, v30\n\t"
        "v_add_f32 v30, 0x38d1b717, v30\n\t"        // + 1e-4f
        "v_sqrt_f32 v30, v30\n\t"
        "s_nop 1\n\t"
        "v_mul_f32 v30, %[ond], v30\n\t"
        "v_exp_f32 v30, v30\n\t"
        "s_nop 1\n\t"
        "v_mul_f32 v24, v24, v30\n\t"
        "v_mul_f32 v25, %[owd], v25\n\t"
        "v_mul_f32 v26, %[orw], v26\n\t"
        // toggle parity LDS addresses
        "v_xor_b32 v4, 32, v4\n\t"
        "v_xor_b32 v5, 32, v5\n\t"
        // commit prefetched scalars, advance, loop
        "s_waitcnt lgkmcnt(0)\n\t"
        "s_mov_b32 s66, s69\n\t"
        "s_mov_b32 s67, s70\n\t"
        "s_mov_b32 s68, s71\n\t"
        "s_mov_b32 s61, s63\n\t"
        "s_mov_b32 s62, s64\n\t"
        "s_add_u32 s60, s60, 1\n\t"
        "s_cmp_lt_u32 s60, 0x100\n\t"
        "s_cbranch_scc1 Lelbo2\n\t"
        "s_waitcnt vmcnt(0)\n\t"                    // drain stores
        :
        : [pys]"s"(ys), [pqs]"s"(qs), [pnz]"s"(nzp), [pou]"s"(out),
          [pzb]"s"(z_biases), [pwi]"s"(w_in), [pwq]"s"(w_inq),
          [vtid]"v"(tid), [ovo]"v"(ovo),
          [osg]"v"(sigb), [otq]"v"(tauq), [omq]"v"(omtq),
          [oty]"v"(tauy), [omy]"v"(omty), [oq]"v"(qscale),
          [ouf]"v"(ufs), [olr]"v"(lr0), [owd]"v"(wd), [orw]"v"(rwd),
          [oos]"v"(oscale), [ond]"v"(nld2)
        : "memory", "scc", "vcc",
          "s60","s61","s62","s63","s64","s65","s66","s67","s68","s69",
          "s70","s71","s72","s73","s74","s75","s76","s77",
          "v1","v2","v3","v4","v5","v6","v7","v8","v9","v10","v11",
          "v12","v13","v14","v15","v16","v17","v18","v19","v20","v21",
          "v22","v23","v24","v25","v26","v27","v28","v29","v30","v31",
          "v32","v33","v34","v35","v36","v37","v38","v39","v40","v41",
          "v42","v43","v44","v45","v46","v47","v48","v49","v50","v51",
          "v52","v53","v54","v55","v56","v57","v58","v59","v60","v61",
          "v62","v63","v64","v65","v66","v67","v68","v69","v70","v71",
          "v72","v73","v74","v75","v76","v77","v78","v79"
    );
}

extern "C" void kernel_launch(void* const* d_in, const int* in_sizes, int n_in,
                              void* d_out, int out_size, void* d_ws, size_t ws_size,
                              hipStream_t stream) {
    (void)in_sizes; (void)n_in; (void)d_ws; (void)ws_size; (void)out_size;
    const float* noises   = (const float*)d_in[0];
    const float* ys       = (const float*)d_in[1];
    const float* qs       = (const float*)d_in[2];
    const float* z_biases = (const float*)d_in[3];
    const float* w_in     = (const float*)d_in[4];
    const float* w_inq    = (const float*)d_in[5];
    const float* llr      = (const float*)d_in[6];
    const float* llrd     = (const float*)d_in[7];
    const float* sigb     = (const float*)d_in[8];
    const float* oscale   = (const float*)d_in[9];
    const float* ufs      = (const float*)d_in[10];
    const float* lwd      = (const float*)d_in[11];
    const float* qscale   = (const float*)d_in[12];
    const float* tauq     = (const float*)d_in[13];
    const float* tauy     = (const float*)d_in[14];
    float* out = (float*)d_out;

    // 64 B dynamic LDS: keeps raw ds addresses 0..63 valid even if the
    // compiler were to drop the static red_lds allocation.
    hipLaunchKernelGGL(legacy_elbo_scan_kernel, dim3(BS), dim3(BLOCK), 64, stream,
                       noises, ys, qs, z_biases, w_in, w_inq,
                       llr, llrd, sigb, oscale, ufs, lwd, qscale, tauq, tauy,
                       out);
}

// Round 9
// 189.259 us; speedup vs baseline: 1.0748x; 1.0748x over previous
//
#include <hip/hip_runtime.h>
#include <math.h>
#include <stdint.h>

#define T_STEPS 256
#define BS      512
#define N       2048
#define BLOCK   256               // 4 waves per batch element, EPT=8
#define FUDGE   1e-4f

// R17: R16 (135us, PASSED) was stalled by lgkmcnt pollution: the pre-barrier
// s_waitcnt lgkmcnt(0) (needed for the lane-63 ds_write2) ALSO waits the 3
// per-step scalar s_loads issued ~200cy earlier (L2 ~300cy) -- exposing
// scalar latency on the critical path every step, ahead of barrier + an
// unshadowed ds_read (~120cy). Fix, structure unchanged from R16:
//  (1) triple-buffered scalar prefetch (A=s66-68, B=s69-71, C=s50-52),
//      issued 3 steps ahead at the POINT AFTER the last lgkm drain of the
//      step -> every in-loop drain sees only >=1-step-old loads (complete).
//  (2) ds_read shadow: ylp update, parity XORs, buffer rotation, counters
//      execute between ds_read issue and its wait.
__global__ __launch_bounds__(BLOCK, 2)
void legacy_elbo_scan_kernel(
    const float* __restrict__ noises,   // [T, BS]
    const float* __restrict__ ys,       // [T]
    const float* __restrict__ qs,       // [T]
    const float* __restrict__ z_biases, // [N]
    const float* __restrict__ w_in,     // [N]
    const float* __restrict__ w_inq,    // [N]
    const float* __restrict__ p_llr,
    const float* __restrict__ p_llrd,
    const float* __restrict__ p_sigb,
    const float* __restrict__ p_oscale,
    const float* __restrict__ p_ufs,
    const float* __restrict__ p_lwd,
    const float* __restrict__ p_qscale,
    const float* __restrict__ p_tauq,
    const float* __restrict__ p_tauy,
    float* __restrict__ out)            // [T, BS]
{
    const int tid = threadIdx.x;
    const int blk = blockIdx.x;

    __shared__ float red_lds[16];       // [parity 2][wave 4][su,sh] = 64 B
    if (tid < 16) red_lds[tid] = 0.0f;  // keep the allocation live, offset 0
    __syncthreads();

    const float sigb    = p_sigb[0];
    const float lr0     = expf(p_llr[0]);
    const float lr_decay= expf(p_llrd[0]);
    const float wd      = expf(p_lwd[0]);
    const float rwd     = 1.0f / wd;
    const float tauq    = 1.0f + log1pf(expf(p_tauq[0]));
    const float tauy    = 1.0f + log1pf(expf(p_tauy[0]));
    const float omtq    = 1.0f - tauq;
    const float omty    = 1.0f - tauy;
    const float qscale  = p_qscale[0];
    const float ufs     = p_ufs[0];
    const float oscale  = p_oscale[0];
    // __expf(x) == exp2(x * log2(e)); fold -lr_decay into the multiplier.
    const float nld2    = -lr_decay * 1.4426950408889634f;

    const float* nzp = noises + blk;    // uniform: per-block noise column base
    const int    ovo = blk * 4;         // byte offset of out[0*BS+blk]

    asm volatile(
        // -------- init: ids, masks, LDS addrs, coeff loads -> v40..v63 ------
        "v_lshrrev_b32 v3, 6, %[vtid]\n\t"          // wid (0..3)
        "v_lshlrev_b32 v4, 3, v3\n\t"               // ds write addr = wid*8
        "v_and_b32 v7, 63, %[vtid]\n\t"             // lane id
        "v_cmp_eq_u32 vcc, 63, v7\n\t"              // lane-63 mask
        "s_mov_b64 s[74:75], vcc\n\t"
        "v_cmp_eq_u32 vcc, 0, %[vtid]\n\t"          // tid==0 mask (wave0 only)
        "s_mov_b64 s[76:77], vcc\n\t"
        "v_mov_b32 v5, 0\n\t"                       // ds read base (parity 0)
        "v_lshlrev_b32 v1, 4, %[vtid]\n\t"          // tid*16 bytes
        "v_add_u32 v2, 0x1000, v1\n\t"              // +4096 for chunk 1
        "global_load_dwordx4 v[40:43], v1, %[pzb]\n\t"
        "global_load_dwordx4 v[44:47], v2, %[pzb]\n\t"
        "global_load_dwordx4 v[48:51], v1, %[pwi]\n\t"
        "global_load_dwordx4 v[52:55], v2, %[pwi]\n\t"
        "global_load_dwordx4 v[56:59], v1, %[pwq]\n\t"
        "global_load_dwordx4 v[60:63], v2, %[pwq]\n\t"
        "s_waitcnt vmcnt(0)\n\t"
        // scale biases by sigma_b
        "v_mul_f32 v40, %[osg], v40\n\t"  "v_mul_f32 v41, %[osg], v41\n\t"
        "v_mul_f32 v42, %[osg], v42\n\t"  "v_mul_f32 v43, %[osg], v43\n\t"
        "v_mul_f32 v44, %[osg], v44\n\t"  "v_mul_f32 v45, %[osg], v45\n\t"
        "v_mul_f32 v46, %[osg], v46\n\t"  "v_mul_f32 v47, %[osg], v47\n\t"
        // zero w_out state v64..v71
        "v_mov_b32 v64, 0\n\t" "v_mov_b32 v65, 0\n\t" "v_mov_b32 v66, 0\n\t" "v_mov_b32 v67, 0\n\t"
        "v_mov_b32 v68, 0\n\t" "v_mov_b32 v69, 0\n\t" "v_mov_b32 v70, 0\n\t" "v_mov_b32 v71, 0\n\t"
        // state: qlp v20, ylp v21, u v22, e v23, lr_mult v24, sp v25, rsp v26
        "v_mov_b32 v20, 0\n\t" "v_mov_b32 v21, 0\n\t" "v_mov_b32 v22, 0\n\t" "v_mov_b32 v23, 0\n\t"
        "v_mov_b32 v24, 1.0\n\t" "v_mov_b32 v25, 1.0\n\t" "v_mov_b32 v26, 1.0\n\t"
        "v_mov_b32 v6, %[ovo]\n\t"                  // out byte-offset
        "s_mov_b32 s60, 0\n\t"                      // t
        "s_mov_b32 s61, 12\n\t"                     // y/q byte off for t+3 issue
        "s_mov_b32 s62, 0x1800\n\t"                 // nz byte off for t+3 issue
        // scalar pipeline: A = t0 (s66-68), B = t1 (s69-71), C = t2 (s50-52)
        "s_load_dword s66, %[pys], 0x0\n\t"
        "s_load_dword s67, %[pqs], 0x0\n\t"
        "s_load_dword s68, %[pnz], 0x0\n\t"
        "s_load_dword s69, %[pys], 0x4\n\t"
        "s_load_dword s70, %[pqs], 0x4\n\t"
        "s_load_dword s71, %[pnz], 0x800\n\t"
        "s_load_dword s50, %[pys], 0x8\n\t"
        "s_load_dword s51, %[pqs], 0x8\n\t"
        "s_load_dword s52, %[pnz], 0x1000\n\t"
        "s_waitcnt lgkmcnt(0)\n\t"
        // ---------------- main scan loop ------------------------------------
        "Lelbo3:\n\t"
        // qlp = omtq*qlp + tauq*q ; qsc pair v[10:11]   (uses A: s67)
        "v_mov_b32 v30, s67\n\t"
        "v_mul_f32 v20, %[omq], v20\n\t"
        "v_fmac_f32 v20, %[otq], v30\n\t"
        "v_mul_f32 v10, %[oq], v20\n\t"
        "v_mov_b32 v11, v10\n\t"
        // x = e + nz + ufs*u ; pair v[8:9]   (uses A: s68)
        "v_mov_b32 v8, s68\n\t"
        "v_add_f32 v8, v23, v8\n\t"
        "v_fmac_f32 v8, %[ouf], v22\n\t"
        "v_mov_b32 v9, v8\n\t"
        // zero accumulators su v[12:13], sh v[14:15]
        "v_mov_b32 v12, 0\n\t" "v_mov_b32 v13, 0\n\t"
        "v_mov_b32 v14, 0\n\t" "v_mov_b32 v15, 0\n\t"
        // h = relu(cb + x*cw + qsc*cq)  (4 packed pairs)
        "v_pk_fma_f32 v[72:73], v[10:11], v[56:57], v[40:41]\n\t"
        "v_pk_fma_f32 v[74:75], v[10:11], v[58:59], v[42:43]\n\t"
        "v_pk_fma_f32 v[76:77], v[10:11], v[60:61], v[44:45]\n\t"
        "v_pk_fma_f32 v[78:79], v[10:11], v[62:63], v[46:47]\n\t"
        "v_pk_fma_f32 v[72:73], v[8:9], v[48:49], v[72:73]\n\t"
        "v_pk_fma_f32 v[74:75], v[8:9], v[50:51], v[74:75]\n\t"
        "v_pk_fma_f32 v[76:77], v[8:9], v[52:53], v[76:77]\n\t"
        "v_pk_fma_f32 v[78:79], v[8:9], v[54:55], v[78:79]\n\t"
        "v_max_f32 v72, 0, v72\n\t" "v_max_f32 v73, 0, v73\n\t"
        "v_max_f32 v74, 0, v74\n\t" "v_max_f32 v75, 0, v75\n\t"
        "v_max_f32 v76, 0, v76\n\t" "v_max_f32 v77, 0, v77\n\t"
        "v_max_f32 v78, 0, v78\n\t" "v_max_f32 v79, 0, v79\n\t"
        // su += v.h ; sh += h.h (interleaved chains)
        "v_pk_fma_f32 v[12:13], v[64:65], v[72:73], v[12:13]\n\t"
        "v_pk_fma_f32 v[14:15], v[72:73], v[72:73], v[14:15]\n\t"
        "v_pk_fma_f32 v[12:13], v[66:67], v[74:75], v[12:13]\n\t"
        "v_pk_fma_f32 v[14:15], v[74:75], v[74:75], v[14:15]\n\t"
        "v_pk_fma_f32 v[12:13], v[68:69], v[76:77], v[12:13]\n\t"
        "v_pk_fma_f32 v[14:15], v[76:77], v[76:77], v[14:15]\n\t"
        "v_pk_fma_f32 v[12:13], v[70:71], v[78:79], v[12:13]\n\t"
        "v_pk_fma_f32 v[14:15], v[78:79], v[78:79], v[14:15]\n\t"
        // horizontal: su v12, sh v14
        "v_add_f32 v12, v12, v13\n\t"
        "v_add_f32 v14, v14, v15\n\t"
        // wave reduce to lane 63 (DPP), su v12/tmp v30, sh v14/tmp v31
        "s_nop 1\n\t"
        "v_mov_b32_dpp v30, v12 row_shr:1 row_mask:0xf bank_mask:0xf\n\t"
        "v_mov_b32_dpp v31, v14 row_shr:1 row_mask:0xf bank_mask:0xf\n\t"
        "v_add_f32 v12, v12, v30\n\t"
        "v_add_f32 v14, v14, v31\n\t"
        "s_nop 0\n\t"
        "v_mov_b32_dpp v30, v12 row_shr:2 row_mask:0xf bank_mask:0xf\n\t"
        "v_mov_b32_dpp v31, v14 row_shr:2 row_mask:0xf bank_mask:0xf\n\t"
        "v_add_f32 v12, v12, v30\n\t"
        "v_add_f32 v14, v14, v31\n\t"
        "s_nop 0\n\t"
        "v_mov_b32_dpp v30, v12 row_shr:4 row_mask:0xf bank_mask:0xf\n\t"
        "v_mov_b32_dpp v31, v14 row_shr:4 row_mask:0xf bank_mask:0xf\n\t"
        "v_add_f32 v12, v12, v30\n\t"
        "v_add_f32 v14, v14, v31\n\t"
        "s_nop 0\n\t"
        "v_mov_b32_dpp v30, v12 row_shr:8 row_mask:0xf bank_mask:0xf\n\t"
        "v_mov_b32_dpp v31, v14 row_shr:8 row_mask:0xf bank_mask:0xf\n\t"
        "v_add_f32 v12, v12, v30\n\t"
        "v_add_f32 v14, v14, v31\n\t"
        "s_nop 0\n\t"
        "v_mov_b32_dpp v30, v12 row_bcast:15 row_mask:0xf bank_mask:0xf\n\t"
        "v_mov_b32_dpp v31, v14 row_bcast:15 row_mask:0xf bank_mask:0xf\n\t"
        "v_add_f32 v12, v12, v30\n\t"
        "v_add_f32 v14, v14, v31\n\t"
        "s_nop 0\n\t"
        "v_mov_b32_dpp v30, v12 row_bcast:31 row_mask:0xf bank_mask:0xf\n\t"
        "v_mov_b32_dpp v31, v14 row_bcast:31 row_mask:0xf bank_mask:0xf\n\t"
        "v_add_f32 v12, v12, v30\n\t"
        "v_add_f32 v14, v14, v31\n\t"
        "s_nop 1\n\t"
        // lane 63 publishes this wave's partials {su, sh} to LDS
        "s_and_saveexec_b64 s[72:73], s[74:75]\n\t"
        "ds_write2_b32 v4, v12, v14 offset0:0 offset1:1\n\t"
        "s_mov_b64 exec, s[72:73]\n\t"
        // drains ONLY the ds_write: all outstanding s_loads are >=1 step old
        "s_waitcnt lgkmcnt(0)\n\t"
        "s_barrier\n\t"
        "ds_read_b128 v[32:35], v5\n\t"
        "ds_read_b128 v[36:39], v5 offset:16\n\t"
        // ---- ds_read shadow: all independent of the read ----
        "v_mov_b32 v30, s66\n\t"                    // y_t (A, pre-rotation)
        "v_mul_f32 v21, %[omy], v21\n\t"
        "v_fmac_f32 v21, %[oty], v30\n\t"           // ylp updated
        "v_xor_b32 v4, 32, v4\n\t"                  // parity toggle
        "v_xor_b32 v5, 32, v5\n\t"
        "s_mov_b32 s66, s69\n\t"                    // rotate A <- B
        "s_mov_b32 s67, s70\n\t"
        "s_mov_b32 s68, s71\n\t"
        "s_mov_b32 s69, s50\n\t"                    // rotate B <- C (drained)
        "s_mov_b32 s70, s51\n\t"
        "s_mov_b32 s71, s52\n\t"
        "s_add_u32 s60, s60, 1\n\t"
        // ---- end shadow ----
        "s_waitcnt lgkmcnt(0)\n\t"
        "v_pk_add_f32 v[32:33], v[32:33], v[34:35]\n\t"
        "v_pk_add_f32 v[36:37], v[36:37], v[38:39]\n\t"
        "v_pk_add_f32 v[32:33], v[32:33], v[36:37]\n\t"   // su_t v32, sh_t v33
        // u = sp * su_t ; store oscale*u from tid 0 (exec-predicated)
        "v_mul_f32 v22, v25, v32\n\t"
        "v_mul_f32 v30, %[oos], v22\n\t"
        "s_and_saveexec_b64 s[72:73], s[76:77]\n\t"
        "global_store_dword v6, v30, %[pou]\n\t"
        "s_mov_b64 exec, s[72:73]\n\t"
        "v_add_u32 v6, 0x800, v6\n\t"               // next row (+BS*4)
        // e, el, c
        "v_sub_f32 v23, v21, v22\n\t"               // e = ylp - u
        "v_mul_f32 v27, %[olr], v23\n\t"
        "v_mul_f32 v27, v27, v24\n\t"               // el
        "v_mul_f32 v28, v27, v26\n\t"               // c = el*rsp
        "v_mov_b32 v29, v28\n\t"
        // issue C <- scalars(t+3) AFTER the last lgkm drain of this step
        "s_load_dword s50, %[pys], s61\n\t"
        "s_load_dword s51, %[pqs], s61\n\t"
        "s_load_dword s52, %[pnz], s62\n\t"
        "s_add_u32 s61, s61, 4\n\t"
        "s_min_u32 s61, s61, 0x3fc\n\t"
        "s_add_u32 s62, s62, 0x800\n\t"
        "s_min_u32 s62, s62, 0x7f800\n\t"
        // v += c*h (4 packed)
        "v_pk_fma_f32 v[64:65], v[28:29], v[72:73], v[64:65]\n\t"
        "v_pk_fma_f32 v[66:67], v[28:29], v[74:75], v[66:67]\n\t"
        "v_pk_fma_f32 v[68:69], v[28:29], v[76:77], v[68:69]\n\t"
        "v_pk_fma_f32 v[70:71], v[28:29], v[78:79], v[70:71]\n\t"
        // lr_mult *= exp2(nld2 * sqrt(el^2*sh_t + FUDGE)) ; sp, rsp
        "v_mul_f32 v30, v27, v27\n\t"
        "v_mul_f32 v30, v33, v30\n\t"
        "v_add_f32 v30, 0x38d1b717, v30\n\t"        // + 1e-4f
        "v_sqrt_f32 v30, v30\n\t"
        "s_nop 1\n\t"
        "v_mul_f32 v30, %[ond], v30\n\t"
        "v_exp_f32 v30, v30\n\t"
        "s_nop 1\n\t"
        "v_mul_f32 v24, v24, v30\n\t"
        "v_mul_f32 v25, %[owd], v25\n\t"
        "v_mul_f32 v26, %[orw], v26\n\t"
        // loop
        "s_cmp_lt_u32 s60, 0x100\n\t"
        "s_cbranch_scc1 Lelbo3\n\t"
        "s_waitcnt vmcnt(0)\n\t"                    // drain stores
        :
        : [pys]"s"(ys), [pqs]"s"(qs), [pnz]"s"(nzp), [pou]"s"(out),
          [pzb]"s"(z_biases), [pwi]"s"(w_in), [pwq]"s"(w_inq),
          [vtid]"v"(tid), [ovo]"v"(ovo),
          [osg]"v"(sigb), [otq]"v"(tauq), [omq]"v"(omtq),
          [oty]"v"(tauy), [omy]"v"(omty), [oq]"v"(qscale),
          [ouf]"v"(ufs), [olr]"v"(lr0), [owd]"v"(wd), [orw]"v"(rwd),
          [oos]"v"(oscale), [ond]"v"(nld2)
        : "memory", "scc", "vcc",
          "s50","s51","s52",
          "s60","s61","s62","s63","s64","s65","s66","s67","s68","s69",
          "s70","s71","s72","s73","s74","s75","s76","s77",
          "v1","v2","v3","v4","v5","v6","v7","v8","v9","v10","v11",
          "v12","v13","v14","v15","v16","v17","v18","v19","v20","v21",
          "v22","v23","v24","v25","v26","v27","v28","v29","v30","v31",
          "v32","v33","v34","v35","v36","v37","v38","v39","v40","v41",
          "v42","v43","v44","v45","v46","v47","v48","v49","v50","v51",
          "v52","v53","v54","v55","v56","v57","v58","v59","v60","v61",
          "v62","v63","v64","v65","v66","v67","v68","v69","v70","v71",
          "v72","v73","v74","v75","v76","v77","v78","v79"
    );
}

extern "C" void kernel_launch(void* const* d_in, const int* in_sizes, int n_in,
                              void* d_out, int out_size, void* d_ws, size_t ws_size,
                              hipStream_t stream) {
    (void)in_sizes; (void)n_in; (void)d_ws; (void)ws_size; (void)out_size;
    const float* noises   = (const float*)d_in[0];
    const float* ys       = (const float*)d_in[1];
    const float* qs       = (const float*)d_in[2];
    const float* z_biases = (const float*)d_in[3];
    const float* w_in     = (const float*)d_in[4];
    const float* w_inq    = (const float*)d_in[5];
    const float* llr      = (const float*)d_in[6];
    const float* llrd     = (const float*)d_in[7];
    const float* sigb     = (const float*)d_in[8];
    const float* oscale   = (const float*)d_in[9];
    const float* ufs      = (const float*)d_in[10];
    const float* lwd      = (const float*)d_in[11];
    const float* qscale   = (const float*)d_in[12];
    const float* tauq     = (const float*)d_in[13];
    const float* tauy     = (const float*)d_in[14];
    float* out = (float*)d_out;

    // 64 B dynamic LDS: keeps raw ds addresses 0..63 valid even if the
    // compiler were to drop the static red_lds allocation.
    hipLaunchKernelGGL(legacy_elbo_scan_kernel, dim3(BS), dim3(BLOCK), 64, stream,
                       noises, ys, qs, z_biases, w_in, w_inq,
                       llr, llrd, sigb, oscale, ufs, lwd, qscale, tauq, tauy,
                       out);
}